// Round 15
// baseline (96.409 us; speedup 1.0000x reference)
//
#include <hip/hip_runtime.h>
#include <math.h>

#define PB 32
#define GB 24
#define NBUK 48
#define NH 256         // hist/scatter blocks
#define SL 16          // slices per bucket in accum
#define PART 160       // floats per accum-block partial: [5][32]

// ---------------- K_hist: per-block bucket histogram ----------------
__global__ __launch_bounds__(256) void k_hist(const int* __restrict__ gi, int NV,
                                              int* __restrict__ counts)
{
    __shared__ int h[NBUK];
    int t = threadIdx.x;
    if (t < NBUK) h[t] = 0;
    __syncthreads();
    int CH = (NV + NH - 1) / NH;
    int lo = blockIdx.x * CH, hi = lo + CH; if (hi > NV) hi = NV;
    for (int i = lo + t; i < hi; i += 256) atomicAdd(&h[gi[i]], 1);
    __syncthreads();
    if (t < NBUK) counts[t * NH + blockIdx.x] = h[t];
}

// ---------------- K_scan: exclusive scan (bucket-major) -> per-(bucket,block) offsets ----------------
__global__ __launch_bounds__(1024) void k_scan(const int* __restrict__ counts,
                                               int* __restrict__ offs, int* __restrict__ bs)
{
    __shared__ int tot[NBUK];
    __shared__ int bstart[NBUK + 1];
    int t = threadIdx.x, w = t >> 6, lane = t & 63;
    int c[3][4]; int excl[3];
    #pragma unroll
    for (int q = 0; q < 3; ++q) {
        int g = w * 3 + q;
        int base = g * NH + lane * 4;
        int s = 0;
        #pragma unroll
        for (int j = 0; j < 4; ++j) { c[q][j] = counts[base + j]; s += c[q][j]; }
        int inc = s;
        for (int off = 1; off < 64; off <<= 1) {
            int v = __shfl_up(inc, off);
            if (lane >= off) inc += v;
        }
        excl[q] = inc - s;
        int rt = __shfl(inc, 63);
        if (lane == 0) tot[g] = rt;
    }
    __syncthreads();
    if (t == 0) {
        int acc = 0;
        for (int g = 0; g < NBUK; ++g) { bstart[g] = acc; acc += tot[g]; }
        bstart[NBUK] = acc;
        for (int g = 0; g <= NBUK; ++g) bs[g] = bstart[g];
    }
    __syncthreads();
    #pragma unroll
    for (int q = 0; q < 3; ++q) {
        int g = w * 3 + q;
        int run = excl[q] + bstart[g];
        #pragma unroll
        for (int j = 0; j < 4; ++j) { offs[g * NH + lane * 4 + j] = run; run += c[q][j]; }
    }
}

// ---------------- K_scatter: stable rank + scatter (batch-pruned ballot range) ----------------
__global__ __launch_bounds__(256) void k_scatter(const int* __restrict__ gi, int NV,
                                                 const int* __restrict__ offs,
                                                 int* __restrict__ sidx)
{
    __shared__ int cur[NBUK];
    __shared__ int wcnt[4][NBUK];
    int t = threadIdx.x, w = t >> 6, lane = t & 63;
    if (t < NBUK) cur[t] = offs[t * NH + blockIdx.x];
    int CH = (NV + NH - 1) / NH;
    int lo = blockIdx.x * CH, hi = lo + CH; if (hi > NV) hi = NV;
    // batches contiguous in v: this block's buckets lie in [qlo,qhi)
    int qlo = (gi[lo] >= GB) ? GB : 0;
    int qhi = (gi[hi - 1] >= GB) ? NBUK : GB;
    unsigned long long below = (lane == 0) ? 0ull : ((~0ull) >> (64 - lane));

    for (int base = lo; base < hi; base += 256) {
        int v = base + t;
        bool act = (v < hi);
        int g = act ? gi[v] : -1;
        for (int j = t; j < 4 * NBUK; j += 256) (&wcnt[0][0])[j] = 0;
        __syncthreads();
        int rank_in_wave = 0;
        for (int q = qlo; q < qhi; ++q) {
            unsigned long long m = __ballot(g == q);
            if (m) {
                if (g == q) rank_in_wave = __popcll(m & below);
                if (lane == __ffsll((unsigned long long)m) - 1) wcnt[w][q] = __popcll(m);
            }
        }
        __syncthreads();
        if (act) {
            int pre = 0;
            for (int ww = 0; ww < w; ++ww) pre += wcnt[ww][g];
            sidx[cur[g] + pre + rank_in_wave] = v;
        }
        __syncthreads();
        if (t < NBUK) {
            int s = 0;
            for (int ww = 0; ww < 4; ++ww) s += wcnt[ww][t];
            cur[t] += s;
        }
        __syncthreads();
    }
}

// ---------------- K_accum2: uniform-il register accumulation (no atomics) ----------------
__global__ __launch_bounds__(256) void k_accum2(
    const float* __restrict__ logits, const int* __restrict__ sidx,
    const int* __restrict__ bs, float* __restrict__ partials)
{
    int g = blockIdx.x >> 4, s = blockIdx.x & 15;
    int b = (g >= GB) ? 1 : 0;
    int lo = bs[g], hi = bs[g + 1];
    int sz = hi - lo;
    int sl = (sz + SL - 1) / SL;
    int p0 = lo + s * sl, p1 = p0 + sl; if (p1 > hi) p1 = hi;

    int t = threadIdx.x, w = t >> 6, lane = t & 63;
    int vi = lane >> 3, c0 = (lane & 7) * 4;
    int wn = p1 - p0;
    int wl = (wn + 3) / 4;
    int q0 = p0 + w * wl, q1 = q0 + wl; if (q1 > p1) q1 = p1;

    const float* xb = logits + 32 * b + c0;
    float sx[4] = {0,0,0,0}, sg[4] = {0,0,0,0};
    float tn[4] = {0,0,0,0}, ts[4] = {0,0,0,0}, tf[4] = {0,0,0,0};

    #pragma unroll 2
    for (int pos = q0; pos < q1; pos += 8) {
        int pv = pos + vi;
        if (pv < q1) {
            int idx = sidx[pv];
            float4 xq = *(const float4*)(xb + (size_t)idx * 64);
            float xs[4] = {xq.x, xq.y, xq.z, xq.w};
            #pragma unroll
            for (int e = 0; e < 4; ++e) {
                float x  = xs[e];
                float ax = fabsf(x);
                float ex = __expf(-ax);
                float neg = fmaxf(x, 0.f) + __logf(1.f + ex);    // softplus(x)
                float r  = __builtin_amdgcn_rcpf(1.f + ex);
                float sig = (x >= 0.f) ? r : ex * r;             // sigmoid(x)
                sx[e] += x;
                sg[e] += sig;
                tn[e] += neg;
                ts[e] += sig;
                tf[e] += neg * sig * sig;
            }
        }
    }

    // reduce across the 8 voxel-groups (lanes with same lane&7)
    #pragma unroll
    for (int off = 8; off <= 32; off <<= 1) {
        #pragma unroll
        for (int e = 0; e < 4; ++e) {
            sx[e] += __shfl_xor(sx[e], off);
            sg[e] += __shfl_xor(sg[e], off);
            tn[e] += __shfl_xor(tn[e], off);
            ts[e] += __shfl_xor(ts[e], off);
            tf[e] += __shfl_xor(tf[e], off);
        }
    }

    __shared__ float red[4][5][PB];
    if (lane < 8) {
        #pragma unroll
        for (int e = 0; e < 4; ++e) {
            red[w][0][c0 + e] = sx[e];
            red[w][1][c0 + e] = sg[e];
            red[w][2][c0 + e] = tn[e];
            red[w][3][c0 + e] = ts[e];
            red[w][4][c0 + e] = tf[e];
        }
    }
    __syncthreads();
    float* op = partials + (size_t)blockIdx.x * PART;
    for (int j = t; j < PART; j += 256)
        op[j] = (&red[0][0][0])[j] + (&red[1][0][0])[j] + (&red[2][0][0])[j] + (&red[3][0][0])[j];
}

// DPP min over 64 lanes -> uniform scalar (4 row_shr mins + 4 readlanes)
#define DPPMIN(ctrl) { int tdp = __builtin_amdgcn_update_dpp(vbits, vbits, ctrl, 0xf, 0xf, false); \
    vbits = __float_as_int(fminf(__int_as_float(vbits), __int_as_float(tdp))); }
__device__ __forceinline__ float wave_min64(float x) {
    int vbits = __float_as_int(x);
    DPPMIN(0x111); DPPMIN(0x112); DPPMIN(0x114); DPPMIN(0x118);
    float a = __int_as_float(__builtin_amdgcn_readlane(vbits, 15));
    float b = __int_as_float(__builtin_amdgcn_readlane(vbits, 31));
    float c = __int_as_float(__builtin_amdgcn_readlane(vbits, 47));
    float d = __int_as_float(__builtin_amdgcn_readlane(vbits, 63));
    return fminf(fminf(a, b), fminf(c, d));
}

// ---------------- K_final: fused slice-reduce + cost build + warm-started register JV + losses ----------------
__global__ __launch_bounds__(1024) void k_final(
    const float* __restrict__ partials, const int* __restrict__ bs, float* __restrict__ outp)
{
    __shared__ float fs2[NBUK][5][PB];   // per (bucket): sx, ssig, tneg_p, tsig_p, tfoc_p
    __shared__ float tneg[2][PB], tsig[2][PB], tfoc[2][PB];
    __shared__ float cntf[NBUK];
    __shared__ float nvbs[2];
    __shared__ float Ct[2][GB][PB];
    __shared__ float uincr[2][GB];
    __shared__ double bres[2][3];

    int tid = threadIdx.x;
    // fused slice-reduce: sum 16 slices per bucket (1024 threads)
    for (int j = tid; j < NBUK * PART; j += 1024) {
        int g = j / PART, r = j % PART;
        const float* base = partials + (size_t)g * SL * PART + r;
        float s = 0.f;
        #pragma unroll
        for (int k = 0; k < SL; ++k) s += base[(size_t)k * PART];
        (&fs2[0][0][0])[j] = s;
    }
    if (tid < NBUK) cntf[tid] = (float)(bs[tid + 1] - bs[tid]);
    __syncthreads();

    if (tid < 64) {
        int b = tid >> 5, p = tid & 31;
        float a = 0.f, c = 0.f, d = 0.f;
        for (int i = 0; i < GB; ++i) {
            a += fs2[b*GB + i][2][p];
            c += fs2[b*GB + i][3][p];
            d += fs2[b*GB + i][4][p];
        }
        tneg[b][p] = a; tsig[b][p] = c; tfoc[b][p] = d;
    }
    if (tid >= 64 && tid < 66) {
        int b = tid - 64; float s = 0.f;
        for (int i = 0; i < GB; ++i) s += cntf[b*GB + i];
        nvbs[b] = s;
    }
    __syncthreads();

    // cost matrix (L_B=2, L_D=1), float math as reference
    for (int idx = tid; idx < 2*GB*PB; idx += 1024) {
        int b = idx / (GB*PB), r = idx % (GB*PB), i = r / PB, j = r % PB;
        float nv = nvbs[b];
        float sx   = fs2[b*GB + i][0][j];
        float ssig = fs2[b*GB + i][1][j];
        float bceC  = 2.0f * (tneg[b][j] - sx) / nv;
        float diceC = 1.0f - (2.f*ssig + 1.f) / (tsig[b][j] + cntf[b*GB + i] + 1.f);
        Ct[b][i][j] = bceC + diceC;
    }
    __syncthreads();

    // Warm-started register JV Hungarian: wave b = batch b, lane = column j.
    int wave = tid >> 6;
    int lane = tid & 63;
    if (tid < 128) {
        int b = wave;
        int j = lane;
        bool valid = (j >= 1 && j <= PB);
        float u_reg = 0.f;              // lane r: u[r+1]
        float v_reg = 0.f;              // lane j: v[j]
        int   p_reg = 0;                // lane j: p[j]; lane 0 = virtual column 0

        // ---- warm start (no register arrays: u distributed in u_reg lanes) ----
        {
            float vv = 3e38f;
            for (int i = 0; i < GB; ++i) {
                float Crow = valid ? Ct[b][i][j-1] : 3e38f;
                float rm = wave_min64(Crow);
                if (lane == i) u_reg = rm;
                if (valid) vv = fminf(vv, Crow - rm);
            }
            v_reg = valid ? vv : 0.f;
        }
        unsigned rowdone = 0;
        for (int i = 0; i < GB; ++i) {
            float u0 = __int_as_float(__builtin_amdgcn_readlane(__float_as_int(u_reg), i));
            bool z = valid && (p_reg == 0) && ((Ct[b][i][j-1] - u0 - v_reg) == 0.f);
            unsigned long long m = __ballot(z);
            if (m != 0ull) {
                int js = (int)__ffsll(m) - 1;
                if (lane == js) p_reg = i + 1;
                rowdone |= (1u << i);
            }
        }

        // ---- augmenting phases for remaining rows ----
        for (int i = 1; i <= GB; ++i) {
            if (rowdone & (1u << (i - 1))) continue;
            float Mv = 3e38f;
            int   way_reg = 0;
            bool  used = (lane == 0);   // virtual col 0 used from start, Duse=0
            float Duse = 0.f;
            if (lane == 0) p_reg = i;
            if (lane < GB) uincr[b][lane] = 0.f;
            int j0 = 0;
            float D = 0.f;
            for (int it = 0; it < 2*PB + 4; ++it) {
                int i0 = __builtin_amdgcn_readlane(p_reg, j0);
                float u0 = __int_as_float(__builtin_amdgcn_readlane(__float_as_int(u_reg), i0 - 1));
                float Crow = valid ? Ct[b][i0-1][j-1] : 0.f;
                float cur = Crow - u0 - v_reg + D;
                if (valid && !used && cur < Mv) { Mv = cur; way_reg = j0; }
                float cand = (valid && !used) ? Mv : 3e38f;
                float dm = wave_min64(cand);
                unsigned long long msk = __ballot(cand == dm);
                int j1 = (int)__ffsll(msk) - 1;
                D = dm;
                if (lane == j1) { used = true; Duse = dm; }
                j0 = j1;
                int pj0 = __builtin_amdgcn_readlane(p_reg, j0);
                if (pj0 == 0) break;
            }
            // dual updates; terminal column (p_reg==0) contributes 0 -> guard avoids OOB write
            if (used) {
                v_reg -= (D - Duse);               // lane 0's v is a dummy
                if (p_reg > 0) uincr[b][p_reg - 1] = D - Duse;
            }
            // augment along way[] (uniform chain, readlane)
            int jj = j0;
            for (int g2 = 0; g2 < PB + 2 && jj; ++g2) {
                int j1 = __builtin_amdgcn_readlane(way_reg, jj);
                int pj1 = __builtin_amdgcn_readlane(p_reg, j1);
                if (lane == jj) p_reg = pj1;
                jj = j1;
            }
            if (lane < GB) u_reg += uincr[b][lane];
        }

        // per-batch loss components (double for exact final sums)
        double nvbd = (double)nvbs[b];
        double myb = 0.0, myd = 0.0, myf = 0.0, myu = 0.0;
        if (valid) {
            int pj = p_reg;
            int p = j - 1;
            if (pj > 0) {
                int ii = pj - 1;
                myb = ((double)tneg[b][p] - (double)fs2[b*GB + ii][0][p]) / nvbd;
                myd = 1.0 - (2.0*(double)fs2[b*GB + ii][1][p] + 1.0) /
                            ((double)tsig[b][p] + (double)cntf[b*GB + ii] + 1.0);
            } else {
                myf = (double)tfoc[b][p];
                myu = 1.0;
            }
        }
        #pragma unroll
        for (int off = 32; off >= 1; off >>= 1) {
            myb += __shfl_xor(myb, off);
            myd += __shfl_xor(myd, off);
            myf += __shfl_xor(myf, off);
            myu += __shfl_xor(myu, off);
        }
        if (lane == 0) {
            double G = (double)GB;
            double bce  = 2.0 * myb / G;                                  // L_B = 2
            double dice = 1.0 * myd / G;                                  // L_D = 1
            double unm  = (myu > 0.0) ? 7.0 * 0.75 * myf / (myu * nvbd)   // L_U, alpha
                                      : 0.0;
            bres[b][0] = bce; bres[b][1] = dice; bres[b][2] = unm;
        }
    }
    __syncthreads();

    if (tid == 0) {
        double L[5] = {0,0,0,0,0};
        for (int b = 0; b < 2; ++b) {
            double bce = bres[b][0], dice = bres[b][1], unm = bres[b][2];
            double matched = bce + dice;
            double total = matched + unm;
            L[0] += total; L[1] += matched; L[2] += unm; L[3] += bce; L[4] += dice;
        }
        for (int k2 = 0; k2 < 5; ++k2) outp[k2] = (float)(L[k2] / 2.0);
    }
}

extern "C" void kernel_launch(void* const* d_in, const int* in_sizes, int n_in,
                              void* d_out, int out_size, void* d_ws, size_t ws_size,
                              hipStream_t stream)
{
    const float* logits = (const float*)d_in[0];
    const int* gi = (const int*)d_in[2];
    int NV = in_sizes[1];

    int* wsi = (int*)d_ws;
    int* counts = wsi;                       // 48*256
    int* offs   = counts + NBUK * NH;        // 48*256
    int* bs     = offs + NBUK * NH;          // 64
    int* sidx   = bs + 64;                   // NV
    float* partials = (float*)(sidx + NV);   // 768*160

    hipLaunchKernelGGL(k_hist,    dim3(NH), dim3(256), 0, stream, gi, NV, counts);
    hipLaunchKernelGGL(k_scan,    dim3(1), dim3(1024), 0, stream, counts, offs, bs);
    hipLaunchKernelGGL(k_scatter, dim3(NH), dim3(256), 0, stream, gi, NV, offs, sidx);
    hipLaunchKernelGGL(k_accum2,  dim3(NBUK * SL), dim3(256), 0, stream, logits, sidx, bs, partials);
    hipLaunchKernelGGL(k_final,   dim3(1), dim3(1024), 0, stream, partials, bs, (float*)d_out);
}

// Round 16
// 85.915 us; speedup vs baseline: 1.1222x; 1.1222x over previous
//
#include <hip/hip_runtime.h>
#include <math.h>

#define PB 32
#define GB 24
#define NBUK 48
#define NH 256         // hist/scatter blocks
#define SL 16          // slices per bucket in accum
#define PART 160       // floats per accum-block partial: [5][32]

// ---------------- K_hist: per-block bucket histogram ----------------
__global__ __launch_bounds__(256) void k_hist(const int* __restrict__ gi, int NV,
                                              int* __restrict__ counts)
{
    __shared__ int h[NBUK];
    int t = threadIdx.x;
    if (t < NBUK) h[t] = 0;
    __syncthreads();
    int CH = (NV + NH - 1) / NH;
    int lo = blockIdx.x * CH, hi = lo + CH; if (hi > NV) hi = NV;
    for (int i = lo + t; i < hi; i += 256) atomicAdd(&h[gi[i]], 1);
    __syncthreads();
    if (t < NBUK) counts[t * NH + blockIdx.x] = h[t];
}

// ---------------- K_scan: exclusive scan (bucket-major) -> per-(bucket,block) offsets ----------------
__global__ __launch_bounds__(1024) void k_scan(const int* __restrict__ counts,
                                               int* __restrict__ offs, int* __restrict__ bs)
{
    __shared__ int tot[NBUK];
    __shared__ int bstart[NBUK + 1];
    int t = threadIdx.x, w = t >> 6, lane = t & 63;
    int c[3][4]; int excl[3];
    #pragma unroll
    for (int q = 0; q < 3; ++q) {
        int g = w * 3 + q;
        int base = g * NH + lane * 4;
        int s = 0;
        #pragma unroll
        for (int j = 0; j < 4; ++j) { c[q][j] = counts[base + j]; s += c[q][j]; }
        int inc = s;
        for (int off = 1; off < 64; off <<= 1) {
            int v = __shfl_up(inc, off);
            if (lane >= off) inc += v;
        }
        excl[q] = inc - s;
        int rt = __shfl(inc, 63);
        if (lane == 0) tot[g] = rt;
    }
    __syncthreads();
    if (t == 0) {
        int acc = 0;
        for (int g = 0; g < NBUK; ++g) { bstart[g] = acc; acc += tot[g]; }
        bstart[NBUK] = acc;
        for (int g = 0; g <= NBUK; ++g) bs[g] = bstart[g];
    }
    __syncthreads();
    #pragma unroll
    for (int q = 0; q < 3; ++q) {
        int g = w * 3 + q;
        int run = excl[q] + bstart[g];
        #pragma unroll
        for (int j = 0; j < 4; ++j) { offs[g * NH + lane * 4 + j] = run; run += c[q][j]; }
    }
}

// ---------------- K_scatter: stable rank + scatter voxel indices ----------------
__global__ __launch_bounds__(256) void k_scatter(const int* __restrict__ gi, int NV,
                                                 const int* __restrict__ offs,
                                                 int* __restrict__ sidx)
{
    __shared__ int cur[NBUK];
    __shared__ int wcnt[4][NBUK];
    int t = threadIdx.x, w = t >> 6, lane = t & 63;
    if (t < NBUK) cur[t] = offs[t * NH + blockIdx.x];
    int CH = (NV + NH - 1) / NH;
    int lo = blockIdx.x * CH, hi = lo + CH; if (hi > NV) hi = NV;
    unsigned long long below = (lane == 0) ? 0ull : ((~0ull) >> (64 - lane));

    for (int base = lo; base < hi; base += 256) {
        int v = base + t;
        bool act = (v < hi);
        int g = act ? gi[v] : -1;
        for (int j = t; j < 4 * NBUK; j += 256) (&wcnt[0][0])[j] = 0;
        __syncthreads();
        int rank_in_wave = 0;
        for (int q = 0; q < NBUK; ++q) {
            unsigned long long m = __ballot(g == q);
            if (m) {
                if (g == q) rank_in_wave = __popcll(m & below);
                if (lane == __ffsll((unsigned long long)m) - 1) wcnt[w][q] = __popcll(m);
            }
        }
        __syncthreads();
        if (act) {
            int pre = 0;
            for (int ww = 0; ww < w; ++ww) pre += wcnt[ww][g];
            sidx[cur[g] + pre + rank_in_wave] = v;
        }
        __syncthreads();
        if (t < NBUK) {
            int s = 0;
            for (int ww = 0; ww < 4; ++ww) s += wcnt[ww][t];
            cur[t] += s;
        }
        __syncthreads();
    }
}

// ---------------- K_accum2: uniform-il register accumulation (no atomics) ----------------
__global__ __launch_bounds__(256) void k_accum2(
    const float* __restrict__ logits, const int* __restrict__ sidx,
    const int* __restrict__ bs, float* __restrict__ partials)
{
    int g = blockIdx.x >> 4, s = blockIdx.x & 15;
    int b = (g >= GB) ? 1 : 0;
    int lo = bs[g], hi = bs[g + 1];
    int sz = hi - lo;
    int sl = (sz + SL - 1) / SL;
    int p0 = lo + s * sl, p1 = p0 + sl; if (p1 > hi) p1 = hi;

    int t = threadIdx.x, w = t >> 6, lane = t & 63;
    int vi = lane >> 3, c0 = (lane & 7) * 4;
    int wn = p1 - p0;
    int wl = (wn + 3) / 4;
    int q0 = p0 + w * wl, q1 = q0 + wl; if (q1 > p1) q1 = p1;

    const float* xb = logits + 32 * b + c0;
    float sx[4] = {0,0,0,0}, sg[4] = {0,0,0,0};
    float tn[4] = {0,0,0,0}, ts[4] = {0,0,0,0}, tf[4] = {0,0,0,0};

    #pragma unroll 2
    for (int pos = q0; pos < q1; pos += 8) {
        int pv = pos + vi;
        if (pv < q1) {
            int idx = sidx[pv];
            float4 xq = *(const float4*)(xb + (size_t)idx * 64);
            float xs[4] = {xq.x, xq.y, xq.z, xq.w};
            #pragma unroll
            for (int e = 0; e < 4; ++e) {
                float x  = xs[e];
                float ax = fabsf(x);
                float ex = __expf(-ax);
                float neg = fmaxf(x, 0.f) + __logf(1.f + ex);    // softplus(x)
                float r  = __builtin_amdgcn_rcpf(1.f + ex);
                float sig = (x >= 0.f) ? r : ex * r;             // sigmoid(x)
                sx[e] += x;
                sg[e] += sig;
                tn[e] += neg;
                ts[e] += sig;
                tf[e] += neg * sig * sig;
            }
        }
    }

    // reduce across the 8 voxel-groups (lanes with same lane&7)
    #pragma unroll
    for (int off = 8; off <= 32; off <<= 1) {
        #pragma unroll
        for (int e = 0; e < 4; ++e) {
            sx[e] += __shfl_xor(sx[e], off);
            sg[e] += __shfl_xor(sg[e], off);
            tn[e] += __shfl_xor(tn[e], off);
            ts[e] += __shfl_xor(ts[e], off);
            tf[e] += __shfl_xor(tf[e], off);
        }
    }

    __shared__ float red[4][5][PB];
    if (lane < 8) {
        #pragma unroll
        for (int e = 0; e < 4; ++e) {
            red[w][0][c0 + e] = sx[e];
            red[w][1][c0 + e] = sg[e];
            red[w][2][c0 + e] = tn[e];
            red[w][3][c0 + e] = ts[e];
            red[w][4][c0 + e] = tf[e];
        }
    }
    __syncthreads();
    float* op = partials + (size_t)blockIdx.x * PART;
    for (int j = t; j < PART; j += 256)
        op[j] = (&red[0][0][0])[j] + (&red[1][0][0])[j] + (&red[2][0][0])[j] + (&red[3][0][0])[j];
}

// DPP min over 64 lanes -> uniform scalar (4 row_shr mins + 4 readlanes)
#define DPPMIN(ctrl) { int tdp = __builtin_amdgcn_update_dpp(vbits, vbits, ctrl, 0xf, 0xf, false); \
    vbits = __float_as_int(fminf(__int_as_float(vbits), __int_as_float(tdp))); }
__device__ __forceinline__ float wave_min64(float x) {
    int vbits = __float_as_int(x);
    DPPMIN(0x111); DPPMIN(0x112); DPPMIN(0x114); DPPMIN(0x118);
    float a = __int_as_float(__builtin_amdgcn_readlane(vbits, 15));
    float b = __int_as_float(__builtin_amdgcn_readlane(vbits, 31));
    float c = __int_as_float(__builtin_amdgcn_readlane(vbits, 47));
    float d = __int_as_float(__builtin_amdgcn_readlane(vbits, 63));
    return fminf(fminf(a, b), fminf(c, d));
}

// ---------------- K_final: fused slice-reduce + cost build + warm-started register JV + losses ----------------
__global__ __launch_bounds__(1024) void k_final(
    const float* __restrict__ partials, const int* __restrict__ bs, float* __restrict__ outp)
{
    __shared__ float fs2[NBUK][5][PB];   // per (bucket): sx, ssig, tneg_p, tsig_p, tfoc_p
    __shared__ float tneg[2][PB], tsig[2][PB], tfoc[2][PB];
    __shared__ float cntf[NBUK];
    __shared__ float nvbs[2];
    __shared__ float Ct[2][GB][PB];
    __shared__ float uincr[2][GB];
    __shared__ double bres[2][3];

    int tid = threadIdx.x;
    // fused slice-reduce: sum 16 slices per bucket (1024 threads)
    for (int j = tid; j < NBUK * PART; j += 1024) {
        int g = j / PART, r = j % PART;
        const float* base = partials + (size_t)g * SL * PART + r;
        float s = 0.f;
        #pragma unroll
        for (int k = 0; k < SL; ++k) s += base[(size_t)k * PART];
        (&fs2[0][0][0])[j] = s;
    }
    if (tid < NBUK) cntf[tid] = (float)(bs[tid + 1] - bs[tid]);
    __syncthreads();

    if (tid < 64) {
        int b = tid >> 5, p = tid & 31;
        float a = 0.f, c = 0.f, d = 0.f;
        for (int i = 0; i < GB; ++i) {
            a += fs2[b*GB + i][2][p];
            c += fs2[b*GB + i][3][p];
            d += fs2[b*GB + i][4][p];
        }
        tneg[b][p] = a; tsig[b][p] = c; tfoc[b][p] = d;
    }
    if (tid >= 64 && tid < 66) {
        int b = tid - 64; float s = 0.f;
        for (int i = 0; i < GB; ++i) s += cntf[b*GB + i];
        nvbs[b] = s;
    }
    __syncthreads();

    // cost matrix (L_B=2, L_D=1), float math as reference
    for (int idx = tid; idx < 2*GB*PB; idx += 1024) {
        int b = idx / (GB*PB), r = idx % (GB*PB), i = r / PB, j = r % PB;
        float nv = nvbs[b];
        float sx   = fs2[b*GB + i][0][j];
        float ssig = fs2[b*GB + i][1][j];
        float bceC  = 2.0f * (tneg[b][j] - sx) / nv;
        float diceC = 1.0f - (2.f*ssig + 1.f) / (tsig[b][j] + cntf[b*GB + i] + 1.f);
        Ct[b][i][j] = bceC + diceC;
    }
    __syncthreads();

    // Warm-started register JV Hungarian: wave b = batch b, lane = column j.
    int wave = tid >> 6;
    int lane = tid & 63;
    if (tid < 128) {
        int b = wave;
        int j = lane;
        bool valid = (j >= 1 && j <= PB);
        float u_reg = 0.f;              // lane r: u[r+1]
        float v_reg = 0.f;              // lane j: v[j]
        int   p_reg = 0;                // lane j: p[j]; lane 0 = virtual column 0

        // ---- warm start (no register arrays: u distributed in u_reg lanes) ----
        {
            float vv = 3e38f;
            for (int i = 0; i < GB; ++i) {
                float Crow = valid ? Ct[b][i][j-1] : 3e38f;
                float rm = wave_min64(Crow);
                if (lane == i) u_reg = rm;
                if (valid) vv = fminf(vv, Crow - rm);
            }
            v_reg = valid ? vv : 0.f;
        }
        unsigned rowdone = 0;
        for (int i = 0; i < GB; ++i) {
            float u0 = __int_as_float(__builtin_amdgcn_readlane(__float_as_int(u_reg), i));
            bool z = valid && (p_reg == 0) && ((Ct[b][i][j-1] - u0 - v_reg) == 0.f);
            unsigned long long m = __ballot(z);
            if (m != 0ull) {
                int js = (int)__ffsll(m) - 1;
                if (lane == js) p_reg = i + 1;
                rowdone |= (1u << i);
            }
        }

        // ---- augmenting phases for remaining rows ----
        for (int i = 1; i <= GB; ++i) {
            if (rowdone & (1u << (i - 1))) continue;
            float Mv = 3e38f;
            int   way_reg = 0;
            bool  used = (lane == 0);   // virtual col 0 used from start, Duse=0
            float Duse = 0.f;
            if (lane == 0) p_reg = i;
            if (lane < GB) uincr[b][lane] = 0.f;
            int j0 = 0;
            float D = 0.f;
            for (int it = 0; it < 2*PB + 4; ++it) {
                int i0 = __builtin_amdgcn_readlane(p_reg, j0);
                float u0 = __int_as_float(__builtin_amdgcn_readlane(__float_as_int(u_reg), i0 - 1));
                float Crow = valid ? Ct[b][i0-1][j-1] : 0.f;
                float cur = Crow - u0 - v_reg + D;
                if (valid && !used && cur < Mv) { Mv = cur; way_reg = j0; }
                float cand = (valid && !used) ? Mv : 3e38f;
                float dm = wave_min64(cand);
                unsigned long long msk = __ballot(cand == dm);
                int j1 = (int)__ffsll(msk) - 1;
                D = dm;
                if (lane == j1) { used = true; Duse = dm; }
                j0 = j1;
                int pj0 = __builtin_amdgcn_readlane(p_reg, j0);
                if (pj0 == 0) break;
            }
            // dual updates; terminal column (p_reg==0) contributes 0 -> guard avoids OOB write
            if (used) {
                v_reg -= (D - Duse);               // lane 0's v is a dummy
                if (p_reg > 0) uincr[b][p_reg - 1] = D - Duse;
            }
            // augment along way[] (uniform chain, readlane)
            int jj = j0;
            for (int g2 = 0; g2 < PB + 2 && jj; ++g2) {
                int j1 = __builtin_amdgcn_readlane(way_reg, jj);
                int pj1 = __builtin_amdgcn_readlane(p_reg, j1);
                if (lane == jj) p_reg = pj1;
                jj = j1;
            }
            if (lane < GB) u_reg += uincr[b][lane];
        }

        // per-batch loss components (double for exact final sums)
        double nvbd = (double)nvbs[b];
        double myb = 0.0, myd = 0.0, myf = 0.0, myu = 0.0;
        if (valid) {
            int pj = p_reg;
            int p = j - 1;
            if (pj > 0) {
                int ii = pj - 1;
                myb = ((double)tneg[b][p] - (double)fs2[b*GB + ii][0][p]) / nvbd;
                myd = 1.0 - (2.0*(double)fs2[b*GB + ii][1][p] + 1.0) /
                            ((double)tsig[b][p] + (double)cntf[b*GB + ii] + 1.0);
            } else {
                myf = (double)tfoc[b][p];
                myu = 1.0;
            }
        }
        #pragma unroll
        for (int off = 32; off >= 1; off >>= 1) {
            myb += __shfl_xor(myb, off);
            myd += __shfl_xor(myd, off);
            myf += __shfl_xor(myf, off);
            myu += __shfl_xor(myu, off);
        }
        if (lane == 0) {
            double G = (double)GB;
            double bce  = 2.0 * myb / G;                                  // L_B = 2
            double dice = 1.0 * myd / G;                                  // L_D = 1
            double unm  = (myu > 0.0) ? 7.0 * 0.75 * myf / (myu * nvbd)   // L_U, alpha
                                      : 0.0;
            bres[b][0] = bce; bres[b][1] = dice; bres[b][2] = unm;
        }
    }
    __syncthreads();

    if (tid == 0) {
        double L[5] = {0,0,0,0,0};
        for (int b = 0; b < 2; ++b) {
            double bce = bres[b][0], dice = bres[b][1], unm = bres[b][2];
            double matched = bce + dice;
            double total = matched + unm;
            L[0] += total; L[1] += matched; L[2] += unm; L[3] += bce; L[4] += dice;
        }
        for (int k2 = 0; k2 < 5; ++k2) outp[k2] = (float)(L[k2] / 2.0);
    }
}

extern "C" void kernel_launch(void* const* d_in, const int* in_sizes, int n_in,
                              void* d_out, int out_size, void* d_ws, size_t ws_size,
                              hipStream_t stream)
{
    const float* logits = (const float*)d_in[0];
    const int* gi = (const int*)d_in[2];
    int NV = in_sizes[1];

    int* wsi = (int*)d_ws;
    int* counts = wsi;                       // 48*256
    int* offs   = counts + NBUK * NH;        // 48*256
    int* bs     = offs + NBUK * NH;          // 64
    int* sidx   = bs + 64;                   // NV
    float* partials = (float*)(sidx + NV);   // 768*160

    hipLaunchKernelGGL(k_hist,    dim3(NH), dim3(256), 0, stream, gi, NV, counts);
    hipLaunchKernelGGL(k_scan,    dim3(1), dim3(1024), 0, stream, counts, offs, bs);
    hipLaunchKernelGGL(k_scatter, dim3(NH), dim3(256), 0, stream, gi, NV, offs, sidx);
    hipLaunchKernelGGL(k_accum2,  dim3(NBUK * SL), dim3(256), 0, stream, logits, sidx, bs, partials);
    hipLaunchKernelGGL(k_final,   dim3(1), dim3(1024), 0, stream, partials, bs, (float*)d_out);
}